// Round 4
// baseline (471.742 us; speedup 1.0000x reference)
//
#include <hip/hip_runtime.h>

#define D 128
#define NPW 16           // nodes per wave (MFMA tile M)
#define WPB 4            // waves per block
#define BN (NPW * WPB)   // 64 nodes per block
#define AST 132          // a_sh padded k-stride

typedef __attribute__((ext_vector_type(8))) short short8;
typedef __attribute__((ext_vector_type(4))) float f32x4;

// fp32 -> bf16 bits, round-to-nearest-even
__device__ inline unsigned int f2bf_bits(float f) {
    unsigned int u = __float_as_uint(f);
    return (u + 0x7FFFu + ((u >> 16) & 1u)) >> 16;
}

// ---------------- zero int fill ----------------
__global__ __launch_bounds__(256) void zero_int_kernel(int* __restrict__ p, int n) {
    int i = blockIdx.x * blockDim.x + threadIdx.x;
    if (i < n) p[i] = 0;
}

// ---------------- degree histogram ----------------
__global__ __launch_bounds__(256) void hist_kernel(const int* __restrict__ dst,
                                                   int* __restrict__ cnt, int E) {
    int e = blockIdx.x * blockDim.x + threadIdx.x;
    if (e < E) atomicAdd(&cnt[dst[e]], 1);
}

// ---------------- hierarchical scan ----------------
__global__ __launch_bounds__(256) void scan1_kernel(const int* __restrict__ cnt,
                                                    int* __restrict__ partial, int n) {
    __shared__ int ws[4];
    int t = threadIdx.x;
    int base = blockIdx.x * 1024 + t * 4;
    int s = 0;
#pragma unroll
    for (int i = 0; i < 4; ++i)
        if (base + i < n) s += cnt[base + i];
#pragma unroll
    for (int o = 1; o < 64; o <<= 1) s += __shfl_xor(s, o, 64);
    if ((t & 63) == 0) ws[t >> 6] = s;
    __syncthreads();
    if (t == 0) partial[blockIdx.x] = ws[0] + ws[1] + ws[2] + ws[3];
}

__global__ __launch_bounds__(64) void scan_mid_kernel(int* __restrict__ partial, int nb) {
    int l = threadIdx.x;
    int v = (l < nb) ? partial[l] : 0;
    int s = v;
#pragma unroll
    for (int o = 1; o < 64; o <<= 1) {
        int t = __shfl_up(s, o, 64);
        if (l >= o) s += t;
    }
    if (l < nb) partial[l] = s - v;  // exclusive
}

// cnt and cursor may alias (each element touched by exactly one thread)
__global__ __launch_bounds__(256) void scan2_kernel(const int* cnt,
                                                    const int* __restrict__ partial,
                                                    int* __restrict__ off,
                                                    int* cursor, int n) {
    __shared__ int wsum[4];
    int t = threadIdx.x;
    int lane = t & 63, wv = t >> 6;
    int i0 = blockIdx.x * 1024 + t * 4;
    int v0 = 0, v1 = 0, v2 = 0, v3 = 0;
    if (i0 + 0 < n) v0 = cnt[i0 + 0];
    if (i0 + 1 < n) v1 = cnt[i0 + 1];
    if (i0 + 2 < n) v2 = cnt[i0 + 2];
    if (i0 + 3 < n) v3 = cnt[i0 + 3];
    int s = v0 + v1 + v2 + v3;
    int sc = s;
#pragma unroll
    for (int o = 1; o < 64; o <<= 1) {
        int u = __shfl_up(sc, o, 64);
        if (lane >= o) sc += u;
    }
    if (lane == 63) wsum[wv] = sc;
    __syncthreads();
    int add = partial[blockIdx.x];
    for (int w = 0; w < wv; ++w) add += wsum[w];
    int excl = add + sc - s;
    if (i0 + 0 < n) { cursor[i0 + 0] = excl; off[i0 + 1] = excl + v0; } excl += v0;
    if (i0 + 1 < n) { cursor[i0 + 1] = excl; off[i0 + 2] = excl + v1; } excl += v1;
    if (i0 + 2 < n) { cursor[i0 + 2] = excl; off[i0 + 3] = excl + v2; } excl += v2;
    if (i0 + 3 < n) { cursor[i0 + 3] = excl; off[i0 + 4] = excl + v3; }
    if (blockIdx.x == 0 && t == 0) off[0] = 0;
}

// ---------------- bucket fill: packed (src<<4)|(dst&15), sorted by dst ----------------
__global__ __launch_bounds__(256) void bucket_kernel(const int* __restrict__ src,
                                                     const int* __restrict__ dst,
                                                     int* __restrict__ cursor,
                                                     int* __restrict__ csr_packed, int E) {
    int e = blockIdx.x * blockDim.x + threadIdx.x;
    if (e >= E) return;
    int d = dst[e];
    int pos = atomicAdd(&cursor[d], 1);
    csr_packed[pos] = (src[e] << 4) | (d & 15);
}

// ---------------- weight transpose + bf16 hi/lo split ----------------
__global__ __launch_bounds__(256) void wsplit_kernel(const float* __restrict__ Wl,
                                                     const float* __restrict__ Wr,
                                                     unsigned short* __restrict__ hi,
                                                     unsigned short* __restrict__ lo) {
    int idx = blockIdx.x * 256 + threadIdx.x;  // 0..32767
    int k = idx >> 7;
    int c = idx & 127;
    float v = (k < 128) ? Wl[k * 128 + c] : Wr[(k - 128) * 128 + c];
    unsigned int h = f2bf_bits(v);
    float hf = __uint_as_float(h << 16);
    unsigned int l = f2bf_bits(v - hf);
    hi[c * 256 + k] = (unsigned short)h;
    lo[c * 256 + k] = (unsigned short)l;
}

// ---------------- fused edge-parallel gather-mean + bf16x3 MFMA GEMM ----------------
// Wave owns 16 consecutive nodes = one contiguous CSR segment. Phase A streams
// the segment in 16-row batches (half-wave per row, 8 rows in flight per half,
// batch-ahead index prefetch), folding runs of the same dst in registers and
// flushing on node change via LDS atomicAdd (ds_add_f32). Phase B: register
// MFMA (bf16x3), A-frags scaled by 1/deg at conversion, B-frags streamed from
// the pre-split transposed weight table in global (L1/L2-resident).
__global__ __launch_bounds__(256) void sage_fused(
    const float* __restrict__ feat,
    const int* __restrict__ off,
    const int* __restrict__ csr_packed,
    const unsigned short* __restrict__ wT_hi,   // [128][256]
    const unsigned short* __restrict__ wT_lo,
    const float* __restrict__ bias,
    float* __restrict__ out,
    int n_nodes, int do_relu)
{
    __shared__ float a_sh[WPB][NPW][AST];
    __shared__ float dinv_sh[BN];

    const int tid = threadIdx.x;
    const int wv = tid >> 6;
    const int lane = tid & 63;
    const int half = lane >> 5;
    const int l5 = lane & 31;
    const int n0b = blockIdx.x * BN;
    const int n0w = n0b + wv * NPW;

    // zero accumulators + degree reciprocals
    for (int i = tid; i < WPB * NPW * (AST / 4); i += 256)
        ((f32x4*)a_sh)[i] = (f32x4){0.f, 0.f, 0.f, 0.f};
    if (tid < BN) {
        int n = n0b + tid;
        float dg = 0.f;
        if (n < n_nodes) dg = (float)(off[n + 1] - off[n]);
        dinv_sh[tid] = 1.0f / fmaxf(dg, 1.0f);
    }
    __syncthreads();

    // ---- phase A: edge-parallel gather with segmented register fold ----
    int segStart = 0, segEnd = 0;
    if (n0w < n_nodes) {
        segStart = off[n0w];
        int ntop = n0w + NPW;
        if (ntop > n_nodes) ntop = n_nodes;
        segEnd = off[ntop];
    }
    const float* fb = feat + (size_t)l5 * 4;
    const int rb0 = 8 * half;

    int cur_j = -1;
    f32x4 cur = (f32x4){0.f, 0.f, 0.f, 0.f};

    int e0 = segStart;
    int idxv = 0;
    if (lane < 16 && e0 + lane < segEnd) idxv = csr_packed[e0 + lane];

    while (e0 < segEnd) {
        const int e1 = e0 + 16;
        int idxn = 0;
        if (lane < 16 && e1 + lane < segEnd) idxn = csr_packed[e1 + lane];  // prefetch

        f32x4 v[8];
        int jj[8];
        bool val[8];
#pragma unroll
        for (int p = 0; p < 8; ++p) {
            int pk = __shfl(idxv, rb0 + p, 64);
            bool vd = (e0 + rb0 + p) < segEnd;
            int s = vd ? (pk >> 4) : 0;
            jj[p] = pk & 15;
            val[p] = vd;
            v[p] = *(const f32x4*)(fb + (size_t)s * D);   // 8 loads in flight
        }
#pragma unroll
        for (int p = 0; p < 8; ++p) {
            f32x4 vv = val[p] ? v[p] : (f32x4){0.f, 0.f, 0.f, 0.f};
            int j = val[p] ? jj[p] : cur_j;
            if (j != cur_j) {                 // half-uniform branch
                if (cur_j >= 0) {
                    atomicAdd(&a_sh[wv][cur_j][l5 * 4 + 0], cur.x);
                    atomicAdd(&a_sh[wv][cur_j][l5 * 4 + 1], cur.y);
                    atomicAdd(&a_sh[wv][cur_j][l5 * 4 + 2], cur.z);
                    atomicAdd(&a_sh[wv][cur_j][l5 * 4 + 3], cur.w);
                }
                cur_j = j;
                cur = vv;
            } else {
                cur += vv;
            }
        }
        idxv = idxn;
        e0 = e1;
    }
    if (cur_j >= 0) {
        atomicAdd(&a_sh[wv][cur_j][l5 * 4 + 0], cur.x);
        atomicAdd(&a_sh[wv][cur_j][l5 * 4 + 1], cur.y);
        atomicAdd(&a_sh[wv][cur_j][l5 * 4 + 2], cur.z);
        atomicAdd(&a_sh[wv][cur_j][l5 * 4 + 3], cur.w);
    }
    __syncthreads();

    // ---- phase B: MFMA ----
    const int q = lane >> 4;     // quad: k-group
    const int r16 = lane & 15;   // A row / B col within tile
    f32x4 acc8[8];
#pragma unroll
    for (int t = 0; t < 8; ++t) acc8[t] = (f32x4){0.f, 0.f, 0.f, 0.f};

    const float dinv = dinv_sh[wv * NPW + r16];
    const int xrow = (n0w + r16 < n_nodes) ? (n0w + r16) : (n_nodes - 1);
    const float* xbase = feat + (size_t)xrow * D + q * 8;
    const float* abase = &a_sh[wv][r16][q * 8];
    const size_t wrow = (size_t)r16 * 256 + q * 8;

    for (int ks = 0; ks < 8; ++ks) {
        f32x4 a0, a1;
        if (ks < 4) {
            a0 = *(const f32x4*)(abase + ks * 32) * dinv;
            a1 = *(const f32x4*)(abase + ks * 32 + 4) * dinv;
        } else {
            a0 = *(const f32x4*)(xbase + (ks - 4) * 32);
            a1 = *(const f32x4*)(xbase + (ks - 4) * 32 + 4);
        }
        short8 ahi, alo;
#pragma unroll
        for (int i = 0; i < 8; ++i) {
            float vv = (i < 4) ? a0[i] : a1[i - 4];
            unsigned int h = f2bf_bits(vv);
            float hf = __uint_as_float(h << 16);
            unsigned int l = f2bf_bits(vv - hf);
            ahi[i] = (short)h;
            alo[i] = (short)l;
        }
        const unsigned short* whp = wT_hi + wrow + ks * 32;
        const unsigned short* wlp = wT_lo + wrow + ks * 32;
#pragma unroll
        for (int t = 0; t < 8; ++t) {
            short8 bhi = *(const short8*)(whp + (size_t)t * 16 * 256);
            short8 blo = *(const short8*)(wlp + (size_t)t * 16 * 256);
            acc8[t] = __builtin_amdgcn_mfma_f32_16x16x32_bf16(ahi, bhi, acc8[t], 0, 0, 0);
            acc8[t] = __builtin_amdgcn_mfma_f32_16x16x32_bf16(alo, bhi, acc8[t], 0, 0, 0);
            acc8[t] = __builtin_amdgcn_mfma_f32_16x16x32_bf16(ahi, blo, acc8[t], 0, 0, 0);
        }
    }

    // ---- epilogue: C/D layout col=lane&15, row=quad*4+reg ----
#pragma unroll
    for (int t = 0; t < 8; ++t) {
        const float bv = bias[t * 16 + r16];
#pragma unroll
        for (int r = 0; r < 4; ++r) {
            const int node = n0w + q * 4 + r;
            if (node < n_nodes) {
                float vv = acc8[t][r] + bv;
                if (do_relu) vv = fmaxf(vv, 0.f);
                out[(size_t)node * D + t * 16 + r16] = vv;
            }
        }
    }
}

// ---------------- edge dot-product decode ----------------
__global__ __launch_bounds__(256) void pred_kernel(const float* __restrict__ z,
                                                   const int* __restrict__ ps,
                                                   const int* __restrict__ pd,
                                                   float* __restrict__ out, int EP) {
    int idx = blockIdx.x * blockDim.x + threadIdx.x;
    int e = idx >> 5;
    if (e >= EP) return;
    int l = idx & 31;
    int a = ps[e];
    int b = pd[e];
    f32x4 va = *(const f32x4*)(z + (size_t)a * D + l * 4);
    f32x4 vb = *(const f32x4*)(z + (size_t)b * D + l * 4);
    float p = va.x * vb.x + va.y * vb.y + va.z * vb.z + va.w * vb.w;
#pragma unroll
    for (int off = 16; off > 0; off >>= 1) p += __shfl_xor(p, off, 32);
    if (l == 0) out[e] = p;
}

extern "C" void kernel_launch(void* const* d_in, const int* in_sizes, int n_in,
                              void* d_out, int out_size, void* d_ws, size_t ws_size,
                              hipStream_t stream) {
    const float* x   = (const float*)d_in[0];
    const float* W1l = (const float*)d_in[1];
    const float* b1  = (const float*)d_in[2];
    const float* W1r = (const float*)d_in[3];
    const float* W2l = (const float*)d_in[4];
    const float* b2  = (const float*)d_in[5];
    const float* W2r = (const float*)d_in[6];
    const int* edge_index = (const int*)d_in[7];
    const int* pred_edges = (const int*)d_in[8];
    float* out = (float*)d_out;

    const int N  = in_sizes[0] / D;   // 50000
    const int E  = in_sizes[7] / 2;   // 800000
    const int EP = in_sizes[8] / 2;   // 200000

    const int* src = edge_index;
    const int* dst = edge_index + E;
    const int* ps  = pred_edges;
    const int* pd  = pred_edges + EP;

    // workspace layout
    int* off     = (int*)d_ws;                 // N+1 (padded 50016)
    int* cursor  = off + 50016;                // N (padded 50016)
    int* partial = cursor + 50016;             // 64
    int* csr     = partial + 64;               // E (packed)
    float* h     = (float*)(csr + E);          // N*D
    float* z     = h + (size_t)N * D;          // N*D
    unsigned short* w1T_hi = (unsigned short*)(z + (size_t)N * D);
    unsigned short* w1T_lo = w1T_hi + 32768;
    unsigned short* w2T_hi = w1T_lo + 32768;
    unsigned short* w2T_lo = w2T_hi + 32768;

    const int nscan = (N + 1023) / 1024;       // 49
    const int nblk_sage = (N + BN - 1) / BN;   // 782

    // weight prep (independent of CSR)
    wsplit_kernel<<<128, 256, 0, stream>>>(W1l, W1r, w1T_hi, w1T_lo);
    wsplit_kernel<<<128, 256, 0, stream>>>(W2l, W2r, w2T_hi, w2T_lo);

    // CSR build
    zero_int_kernel<<<(N + 255) / 256, 256, 0, stream>>>(cursor, N);
    hist_kernel<<<(E + 255) / 256, 256, 0, stream>>>(dst, cursor, E);
    scan1_kernel<<<nscan, 256, 0, stream>>>(cursor, partial, N);
    scan_mid_kernel<<<1, 64, 0, stream>>>(partial, nscan);
    scan2_kernel<<<nscan, 256, 0, stream>>>(cursor, partial, off, cursor, N);
    bucket_kernel<<<(E + 255) / 256, 256, 0, stream>>>(src, dst, cursor, csr, E);

    // layer 1: h = relu(mean@W1l + x@W1r + b1)
    sage_fused<<<nblk_sage, 256, 0, stream>>>(x, off, csr, w1T_hi, w1T_lo, b1, h, N, 1);
    // layer 2: z = mean@W2l + h@W2r + b2
    sage_fused<<<nblk_sage, 256, 0, stream>>>(h, off, csr, w2T_hi, w2T_lo, b2, z, N, 0);
    // decode
    pred_kernel<<<(EP * 32 + 255) / 256, 256, 0, stream>>>(z, ps, pd, out, EP);
}

// Round 5
// 440.817 us; speedup vs baseline: 1.0702x; 1.0702x over previous
//
#include <hip/hip_runtime.h>

#define D 128
#define NPW 16           // nodes per wave (MFMA tile M)
#define WPB 4            // waves per block
#define BN (NPW * WPB)   // 64 nodes per block
#define AST 132          // a_sh padded k-stride

typedef __attribute__((ext_vector_type(8))) short short8;
typedef __attribute__((ext_vector_type(4))) float f32x4;

// fp32 -> bf16 bits, round-to-nearest-even
__device__ inline unsigned int f2bf_bits(float f) {
    unsigned int u = __float_as_uint(f);
    return (u + 0x7FFFu + ((u >> 16) & 1u)) >> 16;
}

// ---------------- zero int fill ----------------
__global__ __launch_bounds__(256) void zero_int_kernel(int* __restrict__ p, int n) {
    int i = blockIdx.x * blockDim.x + threadIdx.x;
    if (i < n) p[i] = 0;
}

// ---------------- fp32 -> bf16 cast (RNE), 4 elems/thread ----------------
__global__ __launch_bounds__(256) void cast_bf16_kernel(const float* __restrict__ in,
                                                        unsigned short* __restrict__ outb,
                                                        int n4) {
    int i = blockIdx.x * blockDim.x + threadIdx.x;
    if (i >= n4) return;
    f32x4 v = *(const f32x4*)(in + (size_t)i * 4);
    ushort4 o;
    o.x = (unsigned short)f2bf_bits(v.x);
    o.y = (unsigned short)f2bf_bits(v.y);
    o.z = (unsigned short)f2bf_bits(v.z);
    o.w = (unsigned short)f2bf_bits(v.w);
    *(ushort4*)(outb + (size_t)i * 4) = o;
}

// ---------------- degree histogram ----------------
__global__ __launch_bounds__(256) void hist_kernel(const int* __restrict__ dst,
                                                   int* __restrict__ cnt, int E) {
    int e = blockIdx.x * blockDim.x + threadIdx.x;
    if (e < E) atomicAdd(&cnt[dst[e]], 1);
}

// ---------------- hierarchical scan ----------------
__global__ __launch_bounds__(256) void scan1_kernel(const int* __restrict__ cnt,
                                                    int* __restrict__ partial, int n) {
    __shared__ int ws[4];
    int t = threadIdx.x;
    int base = blockIdx.x * 1024 + t * 4;
    int s = 0;
#pragma unroll
    for (int i = 0; i < 4; ++i)
        if (base + i < n) s += cnt[base + i];
#pragma unroll
    for (int o = 1; o < 64; o <<= 1) s += __shfl_xor(s, o, 64);
    if ((t & 63) == 0) ws[t >> 6] = s;
    __syncthreads();
    if (t == 0) partial[blockIdx.x] = ws[0] + ws[1] + ws[2] + ws[3];
}

__global__ __launch_bounds__(64) void scan_mid_kernel(int* __restrict__ partial, int nb) {
    int l = threadIdx.x;
    int v = (l < nb) ? partial[l] : 0;
    int s = v;
#pragma unroll
    for (int o = 1; o < 64; o <<= 1) {
        int t = __shfl_up(s, o, 64);
        if (l >= o) s += t;
    }
    if (l < nb) partial[l] = s - v;  // exclusive
}

// cnt and cursor may alias (each element touched by exactly one thread)
__global__ __launch_bounds__(256) void scan2_kernel(const int* cnt,
                                                    const int* __restrict__ partial,
                                                    int* __restrict__ off,
                                                    int* cursor, int n) {
    __shared__ int wsum[4];
    int t = threadIdx.x;
    int lane = t & 63, wv = t >> 6;
    int i0 = blockIdx.x * 1024 + t * 4;
    int v0 = 0, v1 = 0, v2 = 0, v3 = 0;
    if (i0 + 0 < n) v0 = cnt[i0 + 0];
    if (i0 + 1 < n) v1 = cnt[i0 + 1];
    if (i0 + 2 < n) v2 = cnt[i0 + 2];
    if (i0 + 3 < n) v3 = cnt[i0 + 3];
    int s = v0 + v1 + v2 + v3;
    int sc = s;
#pragma unroll
    for (int o = 1; o < 64; o <<= 1) {
        int u = __shfl_up(sc, o, 64);
        if (lane >= o) sc += u;
    }
    if (lane == 63) wsum[wv] = sc;
    __syncthreads();
    int add = partial[blockIdx.x];
    for (int w = 0; w < wv; ++w) add += wsum[w];
    int excl = add + sc - s;
    if (i0 + 0 < n) { cursor[i0 + 0] = excl; off[i0 + 1] = excl + v0; } excl += v0;
    if (i0 + 1 < n) { cursor[i0 + 1] = excl; off[i0 + 2] = excl + v1; } excl += v1;
    if (i0 + 2 < n) { cursor[i0 + 2] = excl; off[i0 + 3] = excl + v2; } excl += v2;
    if (i0 + 3 < n) { cursor[i0 + 3] = excl; off[i0 + 4] = excl + v3; }
    if (blockIdx.x == 0 && t == 0) off[0] = 0;
}

// ---------------- bucket fill ----------------
__global__ __launch_bounds__(256) void bucket_kernel(const int* __restrict__ src,
                                                     const int* __restrict__ dst,
                                                     int* __restrict__ cursor,
                                                     int* __restrict__ csr_src, int E) {
    int e = blockIdx.x * blockDim.x + threadIdx.x;
    if (e >= E) return;
    int pos = atomicAdd(&cursor[dst[e]], 1);
    csr_src[pos] = src[e];
}

// ---------------- weight transpose + bf16 hi/lo split ----------------
__global__ __launch_bounds__(256) void wsplit_kernel(const float* __restrict__ Wl,
                                                     const float* __restrict__ Wr,
                                                     unsigned short* __restrict__ hi,
                                                     unsigned short* __restrict__ lo) {
    int idx = blockIdx.x * 256 + threadIdx.x;  // 0..32767
    int k = idx >> 7;
    int c = idx & 127;
    float v = (k < 128) ? Wl[k * 128 + c] : Wr[(k - 128) * 128 + c];
    unsigned int h = f2bf_bits(v);
    float hf = __uint_as_float(h << 16);
    unsigned int l = f2bf_bits(v - hf);
    hi[c * 256 + k] = (unsigned short)h;
    lo[c * 256 + k] = (unsigned short)l;
}

// ---------------- fused gather-mean (bf16 table) + bf16x3 MFMA GEMM ----------------
// Phase A: wave = 16 nodes, half-wave per node (2 concurrent), lane covers 4
// channels (8 B bf16x4 loads; row = 256 B). 8-deep unrolled edge loop, fp32
// accumulate, mean scaled at LDS write. Phase B: register MFMA (bf16x3);
// x-side self term reads fp32 feat (hi/lo split); B-frags stream from the
// pre-split transposed weight table (L2-resident).
__global__ __launch_bounds__(256) void sage_fused(
    const float* __restrict__ feat,             // fp32 rows (self term)
    const unsigned short* __restrict__ featbf,  // bf16 rows (gather)
    const int* __restrict__ off,
    const int* __restrict__ csr_src,
    const unsigned short* __restrict__ wT_hi,   // [128][256]
    const unsigned short* __restrict__ wT_lo,
    const float* __restrict__ bias,
    float* __restrict__ out,
    int n_nodes, int do_relu)
{
    __shared__ float a_sh[WPB][NPW][AST];

    const int tid = threadIdx.x;
    const int wv = tid >> 6;
    const int lane = tid & 63;
    const int half = lane >> 5;
    const int l5 = lane & 31;
    const int n0w = blockIdx.x * BN + wv * NPW;

    // ---- phase A: gather-mean from bf16 table ----
    const unsigned short* fb = featbf + (size_t)l5 * 4;
#pragma unroll 1
    for (int p = 0; p < 8; ++p) {
        const int j = p * 2 + half;
        const int n = n0w + j;
        f32x4 acc = {0.f, 0.f, 0.f, 0.f};
        int start = 0, end = 0;
        if (n < n_nodes) { start = off[n]; end = off[n + 1]; }
        int e = start;
        for (; e + 8 <= end; e += 8) {
            int4 ia = *(const int4*)(csr_src + e);
            int4 ib = *(const int4*)(csr_src + e + 4);
            uint2 r0 = *(const uint2*)(fb + (size_t)ia.x * D);
            uint2 r1 = *(const uint2*)(fb + (size_t)ia.y * D);
            uint2 r2 = *(const uint2*)(fb + (size_t)ia.z * D);
            uint2 r3 = *(const uint2*)(fb + (size_t)ia.w * D);
            uint2 r4 = *(const uint2*)(fb + (size_t)ib.x * D);
            uint2 r5 = *(const uint2*)(fb + (size_t)ib.y * D);
            uint2 r6 = *(const uint2*)(fb + (size_t)ib.z * D);
            uint2 r7 = *(const uint2*)(fb + (size_t)ib.w * D);
#define ACC(r)  acc.x += __uint_as_float(r.x << 16); \
                acc.y += __uint_as_float(r.x & 0xffff0000u); \
                acc.z += __uint_as_float(r.y << 16); \
                acc.w += __uint_as_float(r.y & 0xffff0000u);
            ACC(r0) ACC(r1) ACC(r2) ACC(r3) ACC(r4) ACC(r5) ACC(r6) ACC(r7)
        }
        for (; e < end; ++e) {
            int s = csr_src[e];
            uint2 r = *(const uint2*)(fb + (size_t)s * D);
            ACC(r)
        }
#undef ACC
        float dinv = 1.0f / (float)max(end - start, 1);
        acc *= dinv;
        *(f32x4*)&a_sh[wv][j][l5 * 4] = acc;
    }
    __syncthreads();

    // ---- phase B: MFMA ----
    const int q = lane >> 4;     // quad: k-group
    const int r16 = lane & 15;   // A row / B col within tile
    f32x4 acc8[8];
#pragma unroll
    for (int t = 0; t < 8; ++t) acc8[t] = (f32x4){0.f, 0.f, 0.f, 0.f};

    const int xrow = (n0w + r16 < n_nodes) ? (n0w + r16) : (n_nodes - 1);
    const float* xbase = feat + (size_t)xrow * D + q * 8;
    const float* abase = &a_sh[wv][r16][q * 8];
    const size_t wrow = (size_t)r16 * 256 + q * 8;

    for (int ks = 0; ks < 8; ++ks) {
        f32x4 a0, a1;
        if (ks < 4) {
            a0 = *(const f32x4*)(abase + ks * 32);
            a1 = *(const f32x4*)(abase + ks * 32 + 4);
        } else {
            a0 = *(const f32x4*)(xbase + (ks - 4) * 32);
            a1 = *(const f32x4*)(xbase + (ks - 4) * 32 + 4);
        }
        short8 ahi, alo;
#pragma unroll
        for (int i = 0; i < 8; ++i) {
            float vv = (i < 4) ? a0[i] : a1[i - 4];
            unsigned int h = f2bf_bits(vv);
            float hf = __uint_as_float(h << 16);
            unsigned int l = f2bf_bits(vv - hf);
            ahi[i] = (short)h;
            alo[i] = (short)l;
        }
        const unsigned short* whp = wT_hi + wrow + ks * 32;
        const unsigned short* wlp = wT_lo + wrow + ks * 32;
#pragma unroll
        for (int t = 0; t < 8; ++t) {
            short8 bhi = *(const short8*)(whp + (size_t)t * 16 * 256);
            short8 blo = *(const short8*)(wlp + (size_t)t * 16 * 256);
            acc8[t] = __builtin_amdgcn_mfma_f32_16x16x32_bf16(ahi, bhi, acc8[t], 0, 0, 0);
            acc8[t] = __builtin_amdgcn_mfma_f32_16x16x32_bf16(alo, bhi, acc8[t], 0, 0, 0);
            acc8[t] = __builtin_amdgcn_mfma_f32_16x16x32_bf16(ahi, blo, acc8[t], 0, 0, 0);
        }
    }

    // ---- epilogue: C/D layout col=lane&15, row=quad*4+reg ----
#pragma unroll
    for (int t = 0; t < 8; ++t) {
        const float bv = bias[t * 16 + r16];
#pragma unroll
        for (int r = 0; r < 4; ++r) {
            const int node = n0w + q * 4 + r;
            if (node < n_nodes) {
                float vv = acc8[t][r] + bv;
                if (do_relu) vv = fmaxf(vv, 0.f);
                out[(size_t)node * D + t * 16 + r16] = vv;
            }
        }
    }
}

// ---------------- edge dot-product decode ----------------
__global__ __launch_bounds__(256) void pred_kernel(const float* __restrict__ z,
                                                   const int* __restrict__ ps,
                                                   const int* __restrict__ pd,
                                                   float* __restrict__ out, int EP) {
    int idx = blockIdx.x * blockDim.x + threadIdx.x;
    int e = idx >> 5;
    if (e >= EP) return;
    int l = idx & 31;
    int a = ps[e];
    int b = pd[e];
    f32x4 va = *(const f32x4*)(z + (size_t)a * D + l * 4);
    f32x4 vb = *(const f32x4*)(z + (size_t)b * D + l * 4);
    float p = va.x * vb.x + va.y * vb.y + va.z * vb.z + va.w * vb.w;
#pragma unroll
    for (int off = 16; off > 0; off >>= 1) p += __shfl_xor(p, off, 32);
    if (l == 0) out[e] = p;
}

extern "C" void kernel_launch(void* const* d_in, const int* in_sizes, int n_in,
                              void* d_out, int out_size, void* d_ws, size_t ws_size,
                              hipStream_t stream) {
    const float* x   = (const float*)d_in[0];
    const float* W1l = (const float*)d_in[1];
    const float* b1  = (const float*)d_in[2];
    const float* W1r = (const float*)d_in[3];
    const float* W2l = (const float*)d_in[4];
    const float* b2  = (const float*)d_in[5];
    const float* W2r = (const float*)d_in[6];
    const int* edge_index = (const int*)d_in[7];
    const int* pred_edges = (const int*)d_in[8];
    float* out = (float*)d_out;

    const int N  = in_sizes[0] / D;   // 50000
    const int E  = in_sizes[7] / 2;   // 800000
    const int EP = in_sizes[8] / 2;   // 200000

    const int* src = edge_index;
    const int* dst = edge_index + E;
    const int* ps  = pred_edges;
    const int* pd  = pred_edges + EP;

    // workspace layout
    int* off     = (int*)d_ws;                 // N+1 (padded 50016)
    int* cursor  = off + 50016;                // N (padded 50016)
    int* partial = cursor + 50016;             // 64
    int* csr     = partial + 64;               // E
    float* h     = (float*)(csr + E);          // N*D fp32
    float* z     = h + (size_t)N * D;          // N*D fp32
    unsigned short* w1T_hi = (unsigned short*)(z + (size_t)N * D);
    unsigned short* w1T_lo = w1T_hi + 32768;
    unsigned short* w2T_hi = w1T_lo + 32768;
    unsigned short* w2T_lo = w2T_hi + 32768;
    unsigned short* fbf    = w2T_lo + 32768;   // N*D bf16 (x, then reused for h)

    const int nscan = (N + 1023) / 1024;       // 49
    const int nblk_sage = (N + BN - 1) / BN;   // 782
    const int ncast = (N * D / 4 + 255) / 256; // 6250

    // weight prep + x cast (independent of CSR)
    wsplit_kernel<<<128, 256, 0, stream>>>(W1l, W1r, w1T_hi, w1T_lo);
    wsplit_kernel<<<128, 256, 0, stream>>>(W2l, W2r, w2T_hi, w2T_lo);
    cast_bf16_kernel<<<ncast, 256, 0, stream>>>(x, fbf, N * D / 4);

    // CSR build
    zero_int_kernel<<<(N + 255) / 256, 256, 0, stream>>>(cursor, N);
    hist_kernel<<<(E + 255) / 256, 256, 0, stream>>>(dst, cursor, E);
    scan1_kernel<<<nscan, 256, 0, stream>>>(cursor, partial, N);
    scan_mid_kernel<<<1, 64, 0, stream>>>(partial, nscan);
    scan2_kernel<<<nscan, 256, 0, stream>>>(cursor, partial, off, cursor, N);
    bucket_kernel<<<(E + 255) / 256, 256, 0, stream>>>(src, dst, cursor, csr, E);

    // layer 1: h = relu(mean@W1l + x@W1r + b1)
    sage_fused<<<nblk_sage, 256, 0, stream>>>(x, fbf, off, csr, w1T_hi, w1T_lo, b1, h, N, 1);
    // h cast (reuse fbf)
    cast_bf16_kernel<<<ncast, 256, 0, stream>>>(h, fbf, N * D / 4);
    // layer 2: z = mean@W2l + h@W2r + b2
    sage_fused<<<nblk_sage, 256, 0, stream>>>(h, fbf, off, csr, w2T_hi, w2T_lo, b2, z, N, 0);
    // decode
    pred_kernel<<<(EP * 32 + 255) / 256, 256, 0, stream>>>(z, ps, pd, out, EP);
}

// Round 6
// 408.435 us; speedup vs baseline: 1.1550x; 1.0793x over previous
//
#include <hip/hip_runtime.h>

#define D 128

typedef __attribute__((ext_vector_type(8))) short short8;
typedef __attribute__((ext_vector_type(4))) float f32x4;

// fp32 -> bf16 bits, round-to-nearest-even
__device__ inline unsigned int f2bf_bits(float f) {
    unsigned int u = __float_as_uint(f);
    return (u + 0x7FFFu + ((u >> 16) & 1u)) >> 16;
}

// ---------------- zero int fill ----------------
__global__ __launch_bounds__(256) void zero_int_kernel(int* __restrict__ p, int n) {
    int i = blockIdx.x * blockDim.x + threadIdx.x;
    if (i < n) p[i] = 0;
}

// ---------------- fp32 -> bf16 cast (RNE), 4 elems/thread ----------------
__global__ __launch_bounds__(256) void cast_bf16_kernel(const float* __restrict__ in,
                                                        unsigned short* __restrict__ outb,
                                                        int n4) {
    int i = blockIdx.x * blockDim.x + threadIdx.x;
    if (i >= n4) return;
    f32x4 v = *(const f32x4*)(in + (size_t)i * 4);
    ushort4 o;
    o.x = (unsigned short)f2bf_bits(v.x);
    o.y = (unsigned short)f2bf_bits(v.y);
    o.z = (unsigned short)f2bf_bits(v.z);
    o.w = (unsigned short)f2bf_bits(v.w);
    *(ushort4*)(outb + (size_t)i * 4) = o;
}

// ---------------- degree histogram ----------------
__global__ __launch_bounds__(256) void hist_kernel(const int* __restrict__ dst,
                                                   int* __restrict__ cnt, int E) {
    int e = blockIdx.x * blockDim.x + threadIdx.x;
    if (e < E) atomicAdd(&cnt[dst[e]], 1);
}

// ---------------- hierarchical scan ----------------
__global__ __launch_bounds__(256) void scan1_kernel(const int* __restrict__ cnt,
                                                    int* __restrict__ partial, int n) {
    __shared__ int ws[4];
    int t = threadIdx.x;
    int base = blockIdx.x * 1024 + t * 4;
    int s = 0;
#pragma unroll
    for (int i = 0; i < 4; ++i)
        if (base + i < n) s += cnt[base + i];
#pragma unroll
    for (int o = 1; o < 64; o <<= 1) s += __shfl_xor(s, o, 64);
    if ((t & 63) == 0) ws[t >> 6] = s;
    __syncthreads();
    if (t == 0) partial[blockIdx.x] = ws[0] + ws[1] + ws[2] + ws[3];
}

__global__ __launch_bounds__(64) void scan_mid_kernel(int* __restrict__ partial, int nb) {
    int l = threadIdx.x;
    int v = (l < nb) ? partial[l] : 0;
    int s = v;
#pragma unroll
    for (int o = 1; o < 64; o <<= 1) {
        int t = __shfl_up(s, o, 64);
        if (l >= o) s += t;
    }
    if (l < nb) partial[l] = s - v;  // exclusive
}

// cnt and cursor may alias (each element touched by exactly one thread)
__global__ __launch_bounds__(256) void scan2_kernel(const int* cnt,
                                                    const int* __restrict__ partial,
                                                    int* __restrict__ off,
                                                    int* cursor, int n) {
    __shared__ int wsum[4];
    int t = threadIdx.x;
    int lane = t & 63, wv = t >> 6;
    int i0 = blockIdx.x * 1024 + t * 4;
    int v0 = 0, v1 = 0, v2 = 0, v3 = 0;
    if (i0 + 0 < n) v0 = cnt[i0 + 0];
    if (i0 + 1 < n) v1 = cnt[i0 + 1];
    if (i0 + 2 < n) v2 = cnt[i0 + 2];
    if (i0 + 3 < n) v3 = cnt[i0 + 3];
    int s = v0 + v1 + v2 + v3;
    int sc = s;
#pragma unroll
    for (int o = 1; o < 64; o <<= 1) {
        int u = __shfl_up(sc, o, 64);
        if (lane >= o) sc += u;
    }
    if (lane == 63) wsum[wv] = sc;
    __syncthreads();
    int add = partial[blockIdx.x];
    for (int w = 0; w < wv; ++w) add += wsum[w];
    int excl = add + sc - s;
    if (i0 + 0 < n) { cursor[i0 + 0] = excl; off[i0 + 1] = excl + v0; } excl += v0;
    if (i0 + 1 < n) { cursor[i0 + 1] = excl; off[i0 + 2] = excl + v1; } excl += v1;
    if (i0 + 2 < n) { cursor[i0 + 2] = excl; off[i0 + 3] = excl + v2; } excl += v2;
    if (i0 + 3 < n) { cursor[i0 + 3] = excl; off[i0 + 4] = excl + v3; }
    if (blockIdx.x == 0 && t == 0) off[0] = 0;
}

// ---------------- bucket fill ----------------
__global__ __launch_bounds__(256) void bucket_kernel(const int* __restrict__ src,
                                                     const int* __restrict__ dst,
                                                     int* __restrict__ cursor,
                                                     int* __restrict__ csr_src, int E) {
    int e = blockIdx.x * blockDim.x + threadIdx.x;
    if (e >= E) return;
    int pos = atomicAdd(&cursor[dst[e]], 1);
    csr_src[pos] = src[e];
}

// ---------------- weight transpose + bf16 hi/lo split ----------------
__global__ __launch_bounds__(256) void wsplit_kernel(const float* __restrict__ Wl,
                                                     const float* __restrict__ Wr,
                                                     unsigned short* __restrict__ hi,
                                                     unsigned short* __restrict__ lo) {
    int idx = blockIdx.x * 256 + threadIdx.x;  // 0..32767
    int k = idx >> 7;
    int c = idx & 127;
    float v = (k < 128) ? Wl[k * 128 + c] : Wr[(k - 128) * 128 + c];
    unsigned int h = f2bf_bits(v);
    float hf = __uint_as_float(h << 16);
    unsigned int l = f2bf_bits(v - hf);
    hi[c * 256 + k] = (unsigned short)h;
    lo[c * 256 + k] = (unsigned short)l;
}

// ---------------- standalone gather-mean (bf16 table -> fp32 scaled mean) ----------------
// Half-wave per node; lane covers 4 channels (8 B). 8-deep unroll. Grid 6250
// blocks -> up to full CU occupancy (was grid-limited to 12 waves/CU fused).
__global__ __launch_bounds__(256) void gather_mean_kernel(
    const unsigned short* __restrict__ featbf,
    const int* __restrict__ off,
    const int* __restrict__ csr_src,
    float* __restrict__ agg,     // output: mean rows, pre-scaled by 1/deg
    int n_nodes)
{
    const int hw = (blockIdx.x * 256 + threadIdx.x) >> 5;   // node id
    const int l5 = threadIdx.x & 31;
    if (hw >= n_nodes) return;
    const unsigned short* fb = featbf + (size_t)l5 * 4;
    const int start = off[hw];
    const int end = off[hw + 1];
    f32x4 acc = {0.f, 0.f, 0.f, 0.f};
    int e = start;
    for (; e + 8 <= end; e += 8) {
        int4 ia = *(const int4*)(csr_src + e);
        int4 ib = *(const int4*)(csr_src + e + 4);
        uint2 r0 = *(const uint2*)(fb + (size_t)ia.x * D);
        uint2 r1 = *(const uint2*)(fb + (size_t)ia.y * D);
        uint2 r2 = *(const uint2*)(fb + (size_t)ia.z * D);
        uint2 r3 = *(const uint2*)(fb + (size_t)ia.w * D);
        uint2 r4 = *(const uint2*)(fb + (size_t)ib.x * D);
        uint2 r5 = *(const uint2*)(fb + (size_t)ib.y * D);
        uint2 r6 = *(const uint2*)(fb + (size_t)ib.z * D);
        uint2 r7 = *(const uint2*)(fb + (size_t)ib.w * D);
#define ACC(r)  acc.x += __uint_as_float(r.x << 16); \
                acc.y += __uint_as_float(r.x & 0xffff0000u); \
                acc.z += __uint_as_float(r.y << 16); \
                acc.w += __uint_as_float(r.y & 0xffff0000u);
        ACC(r0) ACC(r1) ACC(r2) ACC(r3) ACC(r4) ACC(r5) ACC(r6) ACC(r7)
    }
    for (; e < end; ++e) {
        int s = csr_src[e];
        uint2 r = *(const uint2*)(fb + (size_t)s * D);
        ACC(r)
    }
#undef ACC
    float dinv = 1.0f / (float)max(end - start, 1);
    acc *= dinv;
    *(f32x4*)(agg + (size_t)hw * D + l5 * 4) = acc;
}

// ---------------- dense MFMA GEMM: out = agg@Wl + self@Wr + b ----------------
// Wave = 16 nodes (MFMA M=16), 4 waves/block = 64 nodes. bf16x3 hi/lo split
// for ~fp32 accuracy. B-frags batched 16/ks to keep loads in flight.
// Epilogue writes fp32 (optional) and bf16 (optional) outputs.
__global__ __launch_bounds__(256) void sage_gemm_kernel(
    const float* __restrict__ agg,              // pre-scaled mean rows
    const float* __restrict__ self,             // fp32 self rows
    const unsigned short* __restrict__ wT_hi,   // [128 cols][256 k]
    const unsigned short* __restrict__ wT_lo,
    const float* __restrict__ bias,
    float* __restrict__ outf,                   // nullable
    unsigned short* __restrict__ outbf,         // nullable
    int n_nodes, int do_relu)
{
    const int tid = threadIdx.x;
    const int wv = tid >> 6;
    const int lane = tid & 63;
    const int q = lane >> 4;     // k-quad
    const int r16 = lane & 15;   // A row / B col within tile
    const int n0w = blockIdx.x * 64 + wv * 16;

    f32x4 acc8[8];
#pragma unroll
    for (int t = 0; t < 8; ++t) acc8[t] = (f32x4){0.f, 0.f, 0.f, 0.f};

    const int arow = (n0w + r16 < n_nodes) ? (n0w + r16) : (n_nodes - 1);
    const float* abase = agg + (size_t)arow * D + q * 8;
    const float* xbase = self + (size_t)arow * D + q * 8;
    const size_t wrow = (size_t)r16 * 256 + q * 8;

    for (int ks = 0; ks < 8; ++ks) {
        f32x4 a0, a1;
        if (ks < 4) {
            a0 = *(const f32x4*)(abase + ks * 32);
            a1 = *(const f32x4*)(abase + ks * 32 + 4);
        } else {
            a0 = *(const f32x4*)(xbase + (ks - 4) * 32);
            a1 = *(const f32x4*)(xbase + (ks - 4) * 32 + 4);
        }
        // B frags batched: 16 independent loads in flight
        short8 BH[8], BL[8];
        const unsigned short* whp = wT_hi + wrow + ks * 32;
        const unsigned short* wlp = wT_lo + wrow + ks * 32;
#pragma unroll
        for (int t = 0; t < 8; ++t) {
            BH[t] = *(const short8*)(whp + (size_t)t * 4096);
            BL[t] = *(const short8*)(wlp + (size_t)t * 4096);
        }
        short8 ahi, alo;
#pragma unroll
        for (int i = 0; i < 8; ++i) {
            float vv = (i < 4) ? a0[i] : a1[i - 4];
            unsigned int h = f2bf_bits(vv);
            float hf = __uint_as_float(h << 16);
            unsigned int l = f2bf_bits(vv - hf);
            ahi[i] = (short)h;
            alo[i] = (short)l;
        }
#pragma unroll
        for (int t = 0; t < 8; ++t) {
            acc8[t] = __builtin_amdgcn_mfma_f32_16x16x32_bf16(ahi, BH[t], acc8[t], 0, 0, 0);
            acc8[t] = __builtin_amdgcn_mfma_f32_16x16x32_bf16(alo, BH[t], acc8[t], 0, 0, 0);
            acc8[t] = __builtin_amdgcn_mfma_f32_16x16x32_bf16(ahi, BL[t], acc8[t], 0, 0, 0);
        }
    }

    // epilogue: C/D layout col=lane&15, row=quad*4+reg
#pragma unroll
    for (int t = 0; t < 8; ++t) {
        const float bv = bias[t * 16 + r16];
#pragma unroll
        for (int r = 0; r < 4; ++r) {
            const int node = n0w + q * 4 + r;
            if (node < n_nodes) {
                float vv = acc8[t][r] + bv;
                if (do_relu) vv = fmaxf(vv, 0.f);
                const size_t o = (size_t)node * D + t * 16 + r16;
                if (outf) outf[o] = vv;
                if (outbf) outbf[o] = (unsigned short)f2bf_bits(vv);
            }
        }
    }
}

// ---------------- edge dot-product decode (bf16 z rows) ----------------
// Half-wave per pred edge; lane covers 4 channels (uint2 = 8 B).
__global__ __launch_bounds__(256) void pred_kernel(const unsigned short* __restrict__ zbf,
                                                   const int* __restrict__ ps,
                                                   const int* __restrict__ pd,
                                                   float* __restrict__ out, int EP) {
    int idx = blockIdx.x * blockDim.x + threadIdx.x;
    int e = idx >> 5;
    if (e >= EP) return;
    int l = idx & 31;
    const unsigned short* fb = zbf + (size_t)l * 4;
    uint2 ra = *(const uint2*)(fb + (size_t)ps[e] * D);
    uint2 rb = *(const uint2*)(fb + (size_t)pd[e] * D);
    float p = __uint_as_float(ra.x << 16)        * __uint_as_float(rb.x << 16)
            + __uint_as_float(ra.x & 0xffff0000u) * __uint_as_float(rb.x & 0xffff0000u)
            + __uint_as_float(ra.y << 16)        * __uint_as_float(rb.y << 16)
            + __uint_as_float(ra.y & 0xffff0000u) * __uint_as_float(rb.y & 0xffff0000u);
#pragma unroll
    for (int off = 16; off > 0; off >>= 1) p += __shfl_xor(p, off, 32);
    if (l == 0) out[e] = p;
}

extern "C" void kernel_launch(void* const* d_in, const int* in_sizes, int n_in,
                              void* d_out, int out_size, void* d_ws, size_t ws_size,
                              hipStream_t stream) {
    const float* x   = (const float*)d_in[0];
    const float* W1l = (const float*)d_in[1];
    const float* b1  = (const float*)d_in[2];
    const float* W1r = (const float*)d_in[3];
    const float* W2l = (const float*)d_in[4];
    const float* b2  = (const float*)d_in[5];
    const float* W2r = (const float*)d_in[6];
    const int* edge_index = (const int*)d_in[7];
    const int* pred_edges = (const int*)d_in[8];
    float* out = (float*)d_out;

    const int N  = in_sizes[0] / D;   // 50000
    const int E  = in_sizes[7] / 2;   // 800000
    const int EP = in_sizes[8] / 2;   // 200000

    const int* src = edge_index;
    const int* dst = edge_index + E;
    const int* ps  = pred_edges;
    const int* pd  = pred_edges + EP;

    // workspace layout
    int* off     = (int*)d_ws;                 // N+1 (padded 50016)
    int* cursor  = off + 50016;                // N (padded 50016)
    int* partial = cursor + 50016;             // 64
    int* csr     = partial + 64;               // E
    float* agg   = (float*)(csr + E);          // N*D fp32 (scaled mean)
    float* h     = agg + (size_t)N * D;        // N*D fp32
    unsigned short* w1T_hi = (unsigned short*)(h + (size_t)N * D);
    unsigned short* w1T_lo = w1T_hi + 32768;
    unsigned short* w2T_hi = w1T_lo + 32768;
    unsigned short* w2T_lo = w2T_hi + 32768;
    unsigned short* fbf    = w2T_lo + 32768;   // N*D bf16 (x -> h -> z, reused)

    const int nscan = (N + 1023) / 1024;          // 49
    const int nblk_gather = (N * 32 + 255) / 256; // 6250
    const int nblk_gemm = (N + 63) / 64;          // 782
    const int ncast = (N * D / 4 + 255) / 256;    // 6250

    // weight prep + x cast (independent of CSR)
    wsplit_kernel<<<128, 256, 0, stream>>>(W1l, W1r, w1T_hi, w1T_lo);
    wsplit_kernel<<<128, 256, 0, stream>>>(W2l, W2r, w2T_hi, w2T_lo);
    cast_bf16_kernel<<<ncast, 256, 0, stream>>>(x, fbf, N * D / 4);

    // CSR build
    zero_int_kernel<<<(N + 255) / 256, 256, 0, stream>>>(cursor, N);
    hist_kernel<<<(E + 255) / 256, 256, 0, stream>>>(dst, cursor, E);
    scan1_kernel<<<nscan, 256, 0, stream>>>(cursor, partial, N);
    scan_mid_kernel<<<1, 64, 0, stream>>>(partial, nscan);
    scan2_kernel<<<nscan, 256, 0, stream>>>(cursor, partial, off, cursor, N);
    bucket_kernel<<<(E + 255) / 256, 256, 0, stream>>>(src, dst, cursor, csr, E);

    // layer 1: h = relu(mean(x)@W1l + x@W1r + b1), also emits hbf (into fbf)
    gather_mean_kernel<<<nblk_gather, 256, 0, stream>>>(fbf, off, csr, agg, N);
    sage_gemm_kernel<<<nblk_gemm, 256, 0, stream>>>(agg, x, w1T_hi, w1T_lo, b1,
                                                    h, fbf, N, 1);
    // layer 2: z = mean(h)@W2l + h@W2r + b2, emits only zbf (into fbf)
    gather_mean_kernel<<<nblk_gather, 256, 0, stream>>>(fbf, off, csr, agg, N);
    sage_gemm_kernel<<<nblk_gemm, 256, 0, stream>>>(agg, h, w2T_hi, w2T_lo, b2,
                                                    (float*)nullptr, fbf, N, 0);
    // decode from bf16 z
    pred_kernel<<<(EP * 32 + 255) / 256, 256, 0, stream>>>(fbf, ps, pd, out, EP);
}

// Round 7
// 326.731 us; speedup vs baseline: 1.4438x; 1.2501x over previous
//
#include <hip/hip_runtime.h>

#define D 128

typedef __attribute__((ext_vector_type(8))) short short8;
typedef __attribute__((ext_vector_type(4))) float f32x4;

// fp32 -> bf16 bits, round-to-nearest-even
__device__ inline unsigned int f2bf_bits(float f) {
    unsigned int u = __float_as_uint(f);
    return (u + 0x7FFFu + ((u >> 16) & 1u)) >> 16;
}

// ---------------- zero int fill ----------------
__global__ __launch_bounds__(256) void zero_int_kernel(int* __restrict__ p, int n) {
    int i = blockIdx.x * blockDim.x + threadIdx.x;
    if (i < n) p[i] = 0;
}

// ---------------- fp32 -> bf16 cast (RNE), 4 elems/thread ----------------
__global__ __launch_bounds__(256) void cast_bf16_kernel(const float* __restrict__ in,
                                                        unsigned short* __restrict__ outb,
                                                        int n4) {
    int i = blockIdx.x * blockDim.x + threadIdx.x;
    if (i >= n4) return;
    f32x4 v = *(const f32x4*)(in + (size_t)i * 4);
    ushort4 o;
    o.x = (unsigned short)f2bf_bits(v.x);
    o.y = (unsigned short)f2bf_bits(v.y);
    o.z = (unsigned short)f2bf_bits(v.z);
    o.w = (unsigned short)f2bf_bits(v.w);
    *(ushort4*)(outb + (size_t)i * 4) = o;
}

// ---------------- degree histogram ----------------
__global__ __launch_bounds__(256) void hist_kernel(const int* __restrict__ dst,
                                                   int* __restrict__ cnt, int E) {
    int e = blockIdx.x * blockDim.x + threadIdx.x;
    if (e < E) atomicAdd(&cnt[dst[e]], 1);
}

// ---------------- hierarchical scan ----------------
__global__ __launch_bounds__(256) void scan1_kernel(const int* __restrict__ cnt,
                                                    int* __restrict__ partial, int n) {
    __shared__ int ws[4];
    int t = threadIdx.x;
    int base = blockIdx.x * 1024 + t * 4;
    int s = 0;
#pragma unroll
    for (int i = 0; i < 4; ++i)
        if (base + i < n) s += cnt[base + i];
#pragma unroll
    for (int o = 1; o < 64; o <<= 1) s += __shfl_xor(s, o, 64);
    if ((t & 63) == 0) ws[t >> 6] = s;
    __syncthreads();
    if (t == 0) partial[blockIdx.x] = ws[0] + ws[1] + ws[2] + ws[3];
}

__global__ __launch_bounds__(64) void scan_mid_kernel(int* __restrict__ partial, int nb) {
    int l = threadIdx.x;
    int v = (l < nb) ? partial[l] : 0;
    int s = v;
#pragma unroll
    for (int o = 1; o < 64; o <<= 1) {
        int t = __shfl_up(s, o, 64);
        if (l >= o) s += t;
    }
    if (l < nb) partial[l] = s - v;  // exclusive
}

// cnt and cursor may alias (each element touched by exactly one thread)
__global__ __launch_bounds__(256) void scan2_kernel(const int* cnt,
                                                    const int* __restrict__ partial,
                                                    int* __restrict__ off,
                                                    int* cursor, int n) {
    __shared__ int wsum[4];
    int t = threadIdx.x;
    int lane = t & 63, wv = t >> 6;
    int i0 = blockIdx.x * 1024 + t * 4;
    int v0 = 0, v1 = 0, v2 = 0, v3 = 0;
    if (i0 + 0 < n) v0 = cnt[i0 + 0];
    if (i0 + 1 < n) v1 = cnt[i0 + 1];
    if (i0 + 2 < n) v2 = cnt[i0 + 2];
    if (i0 + 3 < n) v3 = cnt[i0 + 3];
    int s = v0 + v1 + v2 + v3;
    int sc = s;
#pragma unroll
    for (int o = 1; o < 64; o <<= 1) {
        int u = __shfl_up(sc, o, 64);
        if (lane >= o) sc += u;
    }
    if (lane == 63) wsum[wv] = sc;
    __syncthreads();
    int add = partial[blockIdx.x];
    for (int w = 0; w < wv; ++w) add += wsum[w];
    int excl = add + sc - s;
    if (i0 + 0 < n) { cursor[i0 + 0] = excl; off[i0 + 1] = excl + v0; } excl += v0;
    if (i0 + 1 < n) { cursor[i0 + 1] = excl; off[i0 + 2] = excl + v1; } excl += v1;
    if (i0 + 2 < n) { cursor[i0 + 2] = excl; off[i0 + 3] = excl + v2; } excl += v2;
    if (i0 + 3 < n) { cursor[i0 + 3] = excl; off[i0 + 4] = excl + v3; }
    if (blockIdx.x == 0 && t == 0) off[0] = 0;
}

// ---------------- bucket fill ----------------
__global__ __launch_bounds__(256) void bucket_kernel(const int* __restrict__ src,
                                                     const int* __restrict__ dst,
                                                     int* __restrict__ cursor,
                                                     int* __restrict__ csr_src, int E) {
    int e = blockIdx.x * blockDim.x + threadIdx.x;
    if (e >= E) return;
    int pos = atomicAdd(&cursor[dst[e]], 1);
    csr_src[pos] = src[e];
}

// ---------------- weight pack: B-fragment order + bf16 hi/lo split ----------------
// wpk[t][ks][lane][j]: t = out-col group (0..7), ks = k-step (0..7),
// lane = q*16+r16, j = 0..7. Value = W[k = ks*32 + q*8 + j][c = t*16 + r16],
// where k<128 -> Wl, k>=128 -> Wr. One wave B-load = contiguous 1 KB.
__global__ __launch_bounds__(256) void wsplit_kernel(const float* __restrict__ Wl,
                                                     const float* __restrict__ Wr,
                                                     unsigned short* __restrict__ hi,
                                                     unsigned short* __restrict__ lo) {
    int idx = blockIdx.x * 256 + threadIdx.x;  // 0..32767
    int t = idx >> 12;
    int ks = (idx >> 9) & 7;
    int lane = (idx >> 3) & 63;
    int j = idx & 7;
    int q = lane >> 4, r16 = lane & 15;
    int k = ks * 32 + q * 8 + j;
    int c = t * 16 + r16;
    float v = (k < 128) ? Wl[k * 128 + c] : Wr[(k - 128) * 128 + c];
    unsigned int h = f2bf_bits(v);
    float hf = __uint_as_float(h << 16);
    unsigned int l = f2bf_bits(v - hf);
    hi[idx] = (unsigned short)h;
    lo[idx] = (unsigned short)l;
}

// ---------------- gather-mean (bf16 table -> packed A-fragment fp32) ----------------
// Half-wave per node; lane covers 4 channels (8 B loads). Output written in
// MFMA A-frag order: aggp[tile][ks(0..3)][lane][j] so the GEMM reads it with
// fully-coalesced f32x4 loads.
__global__ __launch_bounds__(256) void gather_mean_kernel(
    const unsigned short* __restrict__ featbf,
    const int* __restrict__ off,
    const int* __restrict__ csr_src,
    float* __restrict__ aggp,
    int n_nodes)
{
    const int hw = (blockIdx.x * 256 + threadIdx.x) >> 5;   // node id
    const int l5 = threadIdx.x & 31;
    if (hw >= n_nodes) return;
    const unsigned short* fb = featbf + (size_t)l5 * 4;
    const int start = off[hw];
    const int end = off[hw + 1];
    f32x4 acc = {0.f, 0.f, 0.f, 0.f};
    int e = start;
    for (; e + 8 <= end; e += 8) {
        int4 ia = *(const int4*)(csr_src + e);
        int4 ib = *(const int4*)(csr_src + e + 4);
        uint2 r0 = *(const uint2*)(fb + (size_t)ia.x * D);
        uint2 r1 = *(const uint2*)(fb + (size_t)ia.y * D);
        uint2 r2 = *(const uint2*)(fb + (size_t)ia.z * D);
        uint2 r3 = *(const uint2*)(fb + (size_t)ia.w * D);
        uint2 r4 = *(const uint2*)(fb + (size_t)ib.x * D);
        uint2 r5 = *(const uint2*)(fb + (size_t)ib.y * D);
        uint2 r6 = *(const uint2*)(fb + (size_t)ib.z * D);
        uint2 r7 = *(const uint2*)(fb + (size_t)ib.w * D);
#define ACC(r)  acc.x += __uint_as_float(r.x << 16); \
                acc.y += __uint_as_float(r.x & 0xffff0000u); \
                acc.z += __uint_as_float(r.y << 16); \
                acc.w += __uint_as_float(r.y & 0xffff0000u);
        ACC(r0) ACC(r1) ACC(r2) ACC(r3) ACC(r4) ACC(r5) ACC(r6) ACC(r7)
    }
    for (; e < end; ++e) {
        int s = csr_src[e];
        uint2 r = *(const uint2*)(fb + (size_t)s * D);
        ACC(r)
    }
#undef ACC
    float dinv = 1.0f / (float)max(end - start, 1);
    acc *= dinv;
    // packed A-frag store: k = l5*4 + i
    const int tile = hw >> 4, r16 = hw & 15;
    const int ks = l5 >> 3, q = (l5 & 7) >> 1, jb = (l5 & 1) * 4;
    const size_t p = ((size_t)(tile * 4 + ks) * 64 + q * 16 + r16) * 8 + jb;
    *(f32x4*)(aggp + p) = acc;
}

// ---------------- dense MFMA GEMM: out = agg@Wl + self@Wr + b ----------------
// Wave = one 16-node M-tile (N=50000 -> 3125 exact tiles). All B loads and
// packed-A loads are contiguous 1 KB wave-reads. bf16x3 hi/lo split for
// ~fp32 accuracy. Epilogue: optional packed-fp32 out (A-frag order for the
// next layer's self term) + optional row-major bf16 out.
__global__ __launch_bounds__(256) void sage_gemm_kernel(
    const float* __restrict__ aggp,             // packed A (k<128)
    const float* __restrict__ selfm,            // packed (self_packed) or row-major fp32
    const unsigned short* __restrict__ wpk_hi,
    const unsigned short* __restrict__ wpk_lo,
    const float* __restrict__ bias,
    float* __restrict__ outp,                   // nullable, packed fp32
    unsigned short* __restrict__ outbf,         // nullable, row-major bf16
    int ntiles, int self_packed, int do_relu)
{
    const int wv = threadIdx.x >> 6;
    const int lane = threadIdx.x & 63;
    const int tile = blockIdx.x * 4 + wv;
    if (tile >= ntiles) return;
    const int q = lane >> 4, r16 = lane & 15;
    const int n0w = tile * 16;

    f32x4 acc8[8];
#pragma unroll
    for (int t = 0; t < 8; ++t) acc8[t] = (f32x4){0.f, 0.f, 0.f, 0.f};

    const float* ap = aggp + (size_t)tile * 2048 + lane * 8;
    const float* spk = selfm + (size_t)tile * 2048 + lane * 8;
    const float* spr = selfm + (size_t)(n0w + r16) * D + q * 8;

    for (int ks = 0; ks < 8; ++ks) {
        f32x4 a0, a1;
        if (ks < 4) {
            a0 = *(const f32x4*)(ap + ks * 512);
            a1 = *(const f32x4*)(ap + ks * 512 + 4);
        } else if (self_packed) {
            a0 = *(const f32x4*)(spk + (ks - 4) * 512);
            a1 = *(const f32x4*)(spk + (ks - 4) * 512 + 4);
        } else {
            a0 = *(const f32x4*)(spr + (ks - 4) * 32);
            a1 = *(const f32x4*)(spr + (ks - 4) * 32 + 4);
        }
        short8 BH[8], BL[8];
        const unsigned short* bh = wpk_hi + (size_t)ks * 512 + lane * 8;
        const unsigned short* bl = wpk_lo + (size_t)ks * 512 + lane * 8;
#pragma unroll
        for (int t = 0; t < 8; ++t) {
            BH[t] = *(const short8*)(bh + (size_t)t * 4096);
            BL[t] = *(const short8*)(bl + (size_t)t * 4096);
        }
        short8 ahi, alo;
#pragma unroll
        for (int i = 0; i < 8; ++i) {
            float vv = (i < 4) ? a0[i] : a1[i - 4];
            unsigned int h = f2bf_bits(vv);
            float hf = __uint_as_float(h << 16);
            unsigned int l = f2bf_bits(vv - hf);
            ahi[i] = (short)h;
            alo[i] = (short)l;
        }
#pragma unroll
        for (int t = 0; t < 8; ++t) {
            acc8[t] = __builtin_amdgcn_mfma_f32_16x16x32_bf16(ahi, BH[t], acc8[t], 0, 0, 0);
            acc8[t] = __builtin_amdgcn_mfma_f32_16x16x32_bf16(alo, BH[t], acc8[t], 0, 0, 0);
            acc8[t] = __builtin_amdgcn_mfma_f32_16x16x32_bf16(ahi, BL[t], acc8[t], 0, 0, 0);
        }
    }

    // epilogue: C/D layout col=lane&15, row=quad*4+reg
#pragma unroll
    for (int t = 0; t < 8; ++t) {
        const float bv = bias[t * 16 + r16];
#pragma unroll
        for (int r = 0; r < 4; ++r) {
            float vv = acc8[t][r] + bv;
            if (do_relu) vv = fmaxf(vv, 0.f);
            if (outp) {
                // packed A-frag index for (node = n0w+q*4+r, col = t*16+r16)
                const size_t p = ((size_t)(tile * 4 + (t >> 1)) * 64
                                  + ((t & 1) * 2 + (r16 >> 3)) * 16 + q * 4 + r) * 8
                                 + (r16 & 7);
                outp[p] = vv;
            }
            if (outbf) {
                outbf[(size_t)(n0w + q * 4 + r) * D + t * 16 + r16] =
                    (unsigned short)f2bf_bits(vv);
            }
        }
    }
}

// ---------------- edge dot-product decode (bf16 z rows) ----------------
__global__ __launch_bounds__(256) void pred_kernel(const unsigned short* __restrict__ zbf,
                                                   const int* __restrict__ ps,
                                                   const int* __restrict__ pd,
                                                   float* __restrict__ out, int EP) {
    int idx = blockIdx.x * blockDim.x + threadIdx.x;
    int e = idx >> 5;
    if (e >= EP) return;
    int l = idx & 31;
    const unsigned short* fb = zbf + (size_t)l * 4;
    uint2 ra = *(const uint2*)(fb + (size_t)ps[e] * D);
    uint2 rb = *(const uint2*)(fb + (size_t)pd[e] * D);
    float p = __uint_as_float(ra.x << 16)         * __uint_as_float(rb.x << 16)
            + __uint_as_float(ra.x & 0xffff0000u) * __uint_as_float(rb.x & 0xffff0000u)
            + __uint_as_float(ra.y << 16)         * __uint_as_float(rb.y << 16)
            + __uint_as_float(ra.y & 0xffff0000u) * __uint_as_float(rb.y & 0xffff0000u);
#pragma unroll
    for (int off = 16; off > 0; off >>= 1) p += __shfl_xor(p, off, 32);
    if (l == 0) out[e] = p;
}

extern "C" void kernel_launch(void* const* d_in, const int* in_sizes, int n_in,
                              void* d_out, int out_size, void* d_ws, size_t ws_size,
                              hipStream_t stream) {
    const float* x   = (const float*)d_in[0];
    const float* W1l = (const float*)d_in[1];
    const float* b1  = (const float*)d_in[2];
    const float* W1r = (const float*)d_in[3];
    const float* W2l = (const float*)d_in[4];
    const float* b2  = (const float*)d_in[5];
    const float* W2r = (const float*)d_in[6];
    const int* edge_index = (const int*)d_in[7];
    const int* pred_edges = (const int*)d_in[8];
    float* out = (float*)d_out;

    const int N  = in_sizes[0] / D;   // 50000
    const int E  = in_sizes[7] / 2;   // 800000
    const int EP = in_sizes[8] / 2;   // 200000

    const int* src = edge_index;
    const int* dst = edge_index + E;
    const int* ps  = pred_edges;
    const int* pd  = pred_edges + EP;

    // workspace layout
    int* off     = (int*)d_ws;                 // N+1 (padded 50016)
    int* cursor  = off + 50016;                // N (padded 50016)
    int* partial = cursor + 50016;             // 64
    int* csr     = partial + 64;               // E
    float* aggp  = (float*)(csr + E);          // N*D fp32 (packed mean)
    float* hpk   = aggp + (size_t)N * D;       // N*D fp32 (packed h)
    unsigned short* w1_hi = (unsigned short*)(hpk + (size_t)N * D);
    unsigned short* w1_lo = w1_hi + 32768;
    unsigned short* w2_hi = w1_lo + 32768;
    unsigned short* w2_lo = w2_hi + 32768;
    unsigned short* fbf   = w2_lo + 32768;     // N*D bf16 (x -> h -> z, reused)

    const int nscan = (N + 1023) / 1024;          // 49
    const int nblk_gather = (N * 32 + 255) / 256; // 6250
    const int ntiles = N / 16;                    // 3125 (N divisible by 16)
    const int nblk_gemm = (ntiles + 3) / 4;       // 782
    const int ncast = (N * D / 4 + 255) / 256;    // 6250

    // weight prep + x cast (independent of CSR)
    wsplit_kernel<<<128, 256, 0, stream>>>(W1l, W1r, w1_hi, w1_lo);
    wsplit_kernel<<<128, 256, 0, stream>>>(W2l, W2r, w2_hi, w2_lo);
    cast_bf16_kernel<<<ncast, 256, 0, stream>>>(x, fbf, N * D / 4);

    // CSR build
    zero_int_kernel<<<(N + 255) / 256, 256, 0, stream>>>(cursor, N);
    hist_kernel<<<(E + 255) / 256, 256, 0, stream>>>(dst, cursor, E);
    scan1_kernel<<<nscan, 256, 0, stream>>>(cursor, partial, N);
    scan_mid_kernel<<<1, 64, 0, stream>>>(partial, nscan);
    scan2_kernel<<<nscan, 256, 0, stream>>>(cursor, partial, off, cursor, N);
    bucket_kernel<<<(E + 255) / 256, 256, 0, stream>>>(src, dst, cursor, csr, E);

    // layer 1: h = relu(mean(x)@W1l + x@W1r + b1) -> hpk (packed) + fbf (bf16)
    gather_mean_kernel<<<nblk_gather, 256, 0, stream>>>(fbf, off, csr, aggp, N);
    sage_gemm_kernel<<<nblk_gemm, 256, 0, stream>>>(aggp, x, w1_hi, w1_lo, b1,
                                                    hpk, fbf, ntiles, 0, 1);
    // layer 2: z = mean(h)@W2l + h@W2r + b2 -> fbf (bf16 z)
    gather_mean_kernel<<<nblk_gather, 256, 0, stream>>>(fbf, off, csr, aggp, N);
    sage_gemm_kernel<<<nblk_gemm, 256, 0, stream>>>(aggp, hpk, w2_hi, w2_lo, b2,
                                                    (float*)nullptr, fbf, ntiles, 1, 0);
    // decode from bf16 z
    pred_kernel<<<(EP * 32 + 255) / 256, 256, 0, stream>>>(fbf, ps, pd, out, EP);
}

// Round 8
// 261.020 us; speedup vs baseline: 1.8073x; 1.2518x over previous
//
#include <hip/hip_runtime.h>

#define D 128

typedef __attribute__((ext_vector_type(8))) short short8;
typedef __attribute__((ext_vector_type(4))) float f32x4;

// fp32 -> bf16 bits, round-to-nearest-even
__device__ inline unsigned int f2bf_bits(float f) {
    unsigned int u = __float_as_uint(f);
    return (u + 0x7FFFu + ((u >> 16) & 1u)) >> 16;
}

// ---------------- fp32 -> bf16 cast + (last block) zero chist / csr pad ----------------
__global__ __launch_bounds__(256) void cast_bf16_kernel(const float* __restrict__ in,
                                                        unsigned short* __restrict__ outb,
                                                        int n4,
                                                        int* __restrict__ chist,
                                                        int* __restrict__ csrpad) {
    if (blockIdx.x == gridDim.x - 1) {
        int t = threadIdx.x;
        chist[t] = 0;
        if (t < 16) csrpad[t] = 0;
        return;
    }
    int i = blockIdx.x * blockDim.x + threadIdx.x;
    if (i >= n4) return;
    f32x4 v = *(const f32x4*)(in + (size_t)i * 4);
    ushort4 o;
    o.x = (unsigned short)f2bf_bits(v.x);
    o.y = (unsigned short)f2bf_bits(v.y);
    o.z = (unsigned short)f2bf_bits(v.z);
    o.w = (unsigned short)f2bf_bits(v.w);
    *(ushort4*)(outb + (size_t)i * 4) = o;
}

// ---------------- pass A: coarse histogram (bucket = dst>>8) via LDS ----------------
__global__ __launch_bounds__(256) void coarse_count_kernel(const int* __restrict__ dst,
                                                           int* __restrict__ chist, int E) {
    __shared__ int h[256];
    h[threadIdx.x] = 0;
    __syncthreads();
    const int stride = gridDim.x * 256;
    for (int e = blockIdx.x * 256 + threadIdx.x; e < E; e += stride)
        atomicAdd(&h[dst[e] >> 8], 1);
    __syncthreads();
    int v = h[threadIdx.x];
    if (v) atomicAdd(&chist[threadIdx.x], v);
}

// ---------------- pass B: scan 256 bucket counts -> cbase (excl, 257) + gcur ----------------
__global__ __launch_bounds__(256) void scan256_kernel(const int* __restrict__ chist,
                                                      int* __restrict__ cbase,
                                                      int* __restrict__ gcur) {
    __shared__ int wsum[4];
    const int t = threadIdx.x, lane = t & 63, wv = t >> 6;
    int v = chist[t];
    int s = v;
#pragma unroll
    for (int o = 1; o < 64; o <<= 1) {
        int u = __shfl_up(s, o, 64);
        if (lane >= o) s += u;
    }
    if (lane == 63) wsum[wv] = s;
    __syncthreads();
    int add = 0;
    for (int w = 0; w < wv; ++w) add += wsum[w];
    cbase[t + 1] = s + add;
    if (t == 0) cbase[0] = 0;
    gcur[t] = s + add - v;
}

// ---------------- pass C: coarse multisplit scatter ----------------
// Block = 4096 edges. LDS-histogram, one global reservation per bucket per
// block, then dense per-bucket runs (~16 entries = 64 B) -> writes merge.
// Entry = (b<<24) | (src<<8) | (dst&255)   [src < 65536, b < 256]
#define CCHUNK 4096
__global__ __launch_bounds__(256) void coarse_scatter_kernel(
    const int* __restrict__ src, const int* __restrict__ dst,
    int* __restrict__ gcur, unsigned int* __restrict__ centries, int E)
{
    __shared__ int h[256];
    __shared__ int base[256];
    __shared__ unsigned int stage[CCHUNK];
    const int t = threadIdx.x;
    const int e0 = blockIdx.x * CCHUNK;
    h[t] = 0;
    __syncthreads();
#pragma unroll
    for (int i = 0; i < 16; ++i) {
        int e = e0 + i * 256 + t;
        unsigned int u = 0xFFFFFFFFu;
        if (e < E) {
            int d = dst[e];
            int s = src[e];
            int b = d >> 8;
            u = ((unsigned)b << 24) | ((unsigned)s << 8) | (unsigned)(d & 255);
            atomicAdd(&h[b], 1);
        }
        stage[i * 256 + t] = u;
    }
    __syncthreads();
    base[t] = atomicAdd(&gcur[t], h[t]);
    __syncthreads();
    h[t] = 0;
    __syncthreads();
#pragma unroll
    for (int i = 0; i < 16; ++i) {
        unsigned int u = stage[i * 256 + t];
        if (u != 0xFFFFFFFFu) {
            int b = u >> 24;
            int r = atomicAdd(&h[b], 1);
            centries[base[b] + r] = u & 0x00FFFFFFu;
        }
    }
}

// ---------------- pass D: fine bucket (one block per coarse bucket) ----------------
// Builds off[] for its 256 dst nodes and the final CSR (src per edge), staged
// in LDS and streamed out coalesced.
#define DCAP 8192
__global__ __launch_bounds__(256) void fine_bucket_kernel(
    const unsigned int* __restrict__ centries,
    const int* __restrict__ cbase,
    int* __restrict__ offo, int* __restrict__ csr, int N, int E)
{
    __shared__ int h[256], ex[256], wsum[4];
    __shared__ int stg[DCAP];
    const int t = threadIdx.x, lane = t & 63, wv = t >> 6;
    const int b = blockIdx.x;
    const int s0 = cbase[b];
    const int cnt = cbase[b + 1] - s0;
    h[t] = 0;
    __syncthreads();
    for (int i = t; i < cnt; i += 256)
        atomicAdd(&h[centries[s0 + i] & 255], 1);
    __syncthreads();
    int v = h[t], s = v;
#pragma unroll
    for (int o = 1; o < 64; o <<= 1) {
        int u = __shfl_up(s, o, 64);
        if (lane >= o) s += u;
    }
    if (lane == 63) wsum[wv] = s;
    __syncthreads();
    int add = 0;
    for (int w = 0; w < wv; ++w) add += wsum[w];
    const int exc = s + add - v;
    ex[t] = exc;
    const int dg = b * 256 + t;
    if (dg < N) offo[dg] = s0 + exc;
    if (b == 0 && t == 0) offo[N] = E;
    h[t] = 0;
    __syncthreads();
    if (cnt <= DCAP) {
        for (int i = t; i < cnt; i += 256) {
            unsigned int u = centries[s0 + i];
            int dl = u & 255;
            int r = atomicAdd(&h[dl], 1);
            stg[ex[dl] + r] = (int)(u >> 8);
        }
        __syncthreads();
        for (int i = t; i < cnt; i += 256)
            csr[s0 + i] = stg[i];
    } else {  // fallback (never for uniform data, kept for correctness)
        for (int i = t; i < cnt; i += 256) {
            unsigned int u = centries[s0 + i];
            int dl = u & 255;
            int r = atomicAdd(&h[dl], 1);
            csr[s0 + ex[dl] + r] = (int)(u >> 8);
        }
    }
}

// ---------------- weight pack (both layers): B-frag order + bf16 hi/lo split ----------------
__global__ __launch_bounds__(256) void wsplit_kernel(const float* __restrict__ W1l,
                                                     const float* __restrict__ W1r,
                                                     const float* __restrict__ W2l,
                                                     const float* __restrict__ W2r,
                                                     unsigned short* __restrict__ h1,
                                                     unsigned short* __restrict__ l1,
                                                     unsigned short* __restrict__ h2,
                                                     unsigned short* __restrict__ l2) {
    int gidx = blockIdx.x * 256 + threadIdx.x;  // 0..65535
    int sel = gidx >> 15;
    int idx = gidx & 32767;
    int t = idx >> 12;
    int ks = (idx >> 9) & 7;
    int lane = (idx >> 3) & 63;
    int j = idx & 7;
    int q = lane >> 4, r16 = lane & 15;
    int k = ks * 32 + q * 8 + j;
    int c = t * 16 + r16;
    const float* Wl = sel ? W2l : W1l;
    const float* Wr = sel ? W2r : W1r;
    float v = (k < 128) ? Wl[k * 128 + c] : Wr[(k - 128) * 128 + c];
    unsigned int h = f2bf_bits(v);
    float hf = __uint_as_float(h << 16);
    unsigned int l = f2bf_bits(v - hf);
    (sel ? h2 : h1)[idx] = (unsigned short)h;
    (sel ? l2 : l1)[idx] = (unsigned short)l;
}

// ---------------- gather-mean (bf16 table -> packed A-fragment fp32) ----------------
// Half-wave per node; lane covers 4 channels (8 B). Masked 16-deep batches:
// always 16 rows in flight (CSR padded by 16; overshoot reads neighbor-node
// edges = harmless prefetch), no serial tail.
__global__ __launch_bounds__(256) void gather_mean_kernel(
    const unsigned short* __restrict__ featbf,
    const int* __restrict__ off,
    const int* __restrict__ csr,
    float* __restrict__ aggp,
    int n_nodes)
{
    const int hw = (blockIdx.x * 256 + threadIdx.x) >> 5;   // node id
    const int l5 = threadIdx.x & 31;
    if (hw >= n_nodes) return;
    const unsigned short* fb = featbf + (size_t)l5 * 4;
    const int start = off[hw];
    const int end = off[hw + 1];
    f32x4 acc = {0.f, 0.f, 0.f, 0.f};
    for (int e = start; e < end; e += 16) {
        int4 ia = *(const int4*)(csr + e);
        int4 ib = *(const int4*)(csr + e + 4);
        int4 ic = *(const int4*)(csr + e + 8);
        int4 id = *(const int4*)(csr + e + 12);
        uint2 r[16];
        r[0]  = *(const uint2*)(fb + (size_t)ia.x * D);
        r[1]  = *(const uint2*)(fb + (size_t)ia.y * D);
        r[2]  = *(const uint2*)(fb + (size_t)ia.z * D);
        r[3]  = *(const uint2*)(fb + (size_t)ia.w * D);
        r[4]  = *(const uint2*)(fb + (size_t)ib.x * D);
        r[5]  = *(const uint2*)(fb + (size_t)ib.y * D);
        r[6]  = *(const uint2*)(fb + (size_t)ib.z * D);
        r[7]  = *(const uint2*)(fb + (size_t)ib.w * D);
        r[8]  = *(const uint2*)(fb + (size_t)ic.x * D);
        r[9]  = *(const uint2*)(fb + (size_t)ic.y * D);
        r[10] = *(const uint2*)(fb + (size_t)ic.z * D);
        r[11] = *(const uint2*)(fb + (size_t)ic.w * D);
        r[12] = *(const uint2*)(fb + (size_t)id.x * D);
        r[13] = *(const uint2*)(fb + (size_t)id.y * D);
        r[14] = *(const uint2*)(fb + (size_t)id.z * D);
        r[15] = *(const uint2*)(fb + (size_t)id.w * D);
#pragma unroll
        for (int p = 0; p < 16; ++p) {
            uint2 rv = r[p];
            if (e + p >= end) { rv.x = 0u; rv.y = 0u; }
            acc.x += __uint_as_float(rv.x << 16);
            acc.y += __uint_as_float(rv.x & 0xffff0000u);
            acc.z += __uint_as_float(rv.y << 16);
            acc.w += __uint_as_float(rv.y & 0xffff0000u);
        }
    }
    float dinv = 1.0f / (float)max(end - start, 1);
    acc *= dinv;
    // packed A-frag store: k = l5*4 + i
    const int tile = hw >> 4, r16 = hw & 15;
    const int ks = l5 >> 3, q = (l5 & 7) >> 1, jb = (l5 & 1) * 4;
    const size_t p = ((size_t)(tile * 4 + ks) * 64 + q * 16 + r16) * 8 + jb;
    *(f32x4*)(aggp + p) = acc;
}

// ---------------- dense MFMA GEMM: out = agg@Wl + self@Wr + b ----------------
__global__ __launch_bounds__(256) void sage_gemm_kernel(
    const float* __restrict__ aggp,             // packed A (k<128)
    const float* __restrict__ selfm,            // packed (self_packed) or row-major fp32
    const unsigned short* __restrict__ wpk_hi,
    const unsigned short* __restrict__ wpk_lo,
    const float* __restrict__ bias,
    float* __restrict__ outp,                   // nullable, packed fp32
    unsigned short* __restrict__ outbf,         // nullable, row-major bf16
    int ntiles, int self_packed, int do_relu)
{
    const int wv = threadIdx.x >> 6;
    const int lane = threadIdx.x & 63;
    const int tile = blockIdx.x * 4 + wv;
    if (tile >= ntiles) return;
    const int q = lane >> 4, r16 = lane & 15;
    const int n0w = tile * 16;

    f32x4 acc8[8];
#pragma unroll
    for (int t = 0; t < 8; ++t) acc8[t] = (f32x4){0.f, 0.f, 0.f, 0.f};

    const float* ap = aggp + (size_t)tile * 2048 + lane * 8;
    const float* spk = selfm + (size_t)tile * 2048 + lane * 8;
    const float* spr = selfm + (size_t)(n0w + r16) * D + q * 8;

    for (int ks = 0; ks < 8; ++ks) {
        f32x4 a0, a1;
        if (ks < 4) {
            a0 = *(const f32x4*)(ap + ks * 512);
            a1 = *(const f32x4*)(ap + ks * 512 + 4);
        } else if (self_packed) {
            a0 = *(const f32x4*)(spk + (ks - 4) * 512);
            a1 = *(const f32x4*)(spk + (ks - 4) * 512 + 4);
        } else {
            a0 = *(const f32x4*)(spr + (ks - 4) * 32);
            a1 = *(const f32x4*)(spr + (ks - 4) * 32 + 4);
        }
        short8 BH[8], BL[8];
        const unsigned short* bh = wpk_hi + (size_t)ks * 512 + lane * 8;
        const unsigned short* bl = wpk_lo + (size_t)ks * 512 + lane * 8;
#pragma unroll
        for (int t = 0; t < 8; ++t) {
            BH[t] = *(const short8*)(bh + (size_t)t * 4096);
            BL[t] = *(const short8*)(bl + (size_t)t * 4096);
        }
        short8 ahi, alo;
#pragma unroll
        for (int i = 0; i < 8; ++i) {
            float vv = (i < 4) ? a0[i] : a1[i - 4];
            unsigned int h = f2bf_bits(vv);
            float hf = __uint_as_float(h << 16);
            unsigned int l = f2bf_bits(vv - hf);
            ahi[i] = (short)h;
            alo[i] = (short)l;
        }
#pragma unroll
        for (int t = 0; t < 8; ++t) {
            acc8[t] = __builtin_amdgcn_mfma_f32_16x16x32_bf16(ahi, BH[t], acc8[t], 0, 0, 0);
            acc8[t] = __builtin_amdgcn_mfma_f32_16x16x32_bf16(alo, BH[t], acc8[t], 0, 0, 0);
            acc8[t] = __builtin_amdgcn_mfma_f32_16x16x32_bf16(ahi, BL[t], acc8[t], 0, 0, 0);
        }
    }

    // epilogue: C/D layout col=lane&15, row=quad*4+reg
#pragma unroll
    for (int t = 0; t < 8; ++t) {
        const float bv = bias[t * 16 + r16];
#pragma unroll
        for (int r = 0; r < 4; ++r) {
            float vv = acc8[t][r] + bv;
            if (do_relu) vv = fmaxf(vv, 0.f);
            if (outp) {
                const size_t p = ((size_t)(tile * 4 + (t >> 1)) * 64
                                  + ((t & 1) * 2 + (r16 >> 3)) * 16 + q * 4 + r) * 8
                                 + (r16 & 7);
                outp[p] = vv;
            }
            if (outbf) {
                outbf[(size_t)(n0w + q * 4 + r) * D + t * 16 + r16] =
                    (unsigned short)f2bf_bits(vv);
            }
        }
    }
}

// ---------------- edge dot-product decode (bf16 z rows) ----------------
__global__ __launch_bounds__(256) void pred_kernel(const unsigned short* __restrict__ zbf,
                                                   const int* __restrict__ ps,
                                                   const int* __restrict__ pd,
                                                   float* __restrict__ out, int EP) {
    int idx = blockIdx.x * blockDim.x + threadIdx.x;
    int e = idx >> 5;
    if (e >= EP) return;
    int l = idx & 31;
    const unsigned short* fb = zbf + (size_t)l * 4;
    uint2 ra = *(const uint2*)(fb + (size_t)ps[e] * D);
    uint2 rb = *(const uint2*)(fb + (size_t)pd[e] * D);
    float p = __uint_as_float(ra.x << 16)         * __uint_as_float(rb.x << 16)
            + __uint_as_float(ra.x & 0xffff0000u) * __uint_as_float(rb.x & 0xffff0000u)
            + __uint_as_float(ra.y << 16)         * __uint_as_float(rb.y << 16)
            + __uint_as_float(ra.y & 0xffff0000u) * __uint_as_float(rb.y & 0xffff0000u);
#pragma unroll
    for (int off = 16; off > 0; off >>= 1) p += __shfl_xor(p, off, 32);
    if (l == 0) out[e] = p;
}

extern "C" void kernel_launch(void* const* d_in, const int* in_sizes, int n_in,
                              void* d_out, int out_size, void* d_ws, size_t ws_size,
                              hipStream_t stream) {
    const float* x   = (const float*)d_in[0];
    const float* W1l = (const float*)d_in[1];
    const float* b1  = (const float*)d_in[2];
    const float* W1r = (const float*)d_in[3];
    const float* W2l = (const float*)d_in[4];
    const float* b2  = (const float*)d_in[5];
    const float* W2r = (const float*)d_in[6];
    const int* edge_index = (const int*)d_in[7];
    const int* pred_edges = (const int*)d_in[8];
    float* out = (float*)d_out;

    const int N  = in_sizes[0] / D;   // 50000
    const int E  = in_sizes[7] / 2;   // 800000
    const int EP = in_sizes[8] / 2;   // 200000

    const int* src = edge_index;
    const int* dst = edge_index + E;
    const int* ps  = pred_edges;
    const int* pd  = pred_edges + EP;

    // workspace layout
    int* chist   = (int*)d_ws;                 // 256
    int* cbase   = chist + 256;                // 257 (pad 272)
    int* gcur    = cbase + 272;                // 256
    int* off     = gcur + 256;                 // N+1 (pad 50016)
    unsigned int* centries = (unsigned int*)(off + 50016);  // E
    int* csr     = (int*)(centries + E);       // E + 16 pad
    float* aggp  = (float*)(csr + E + 16);     // N*D fp32 (packed mean)
    float* hpk   = aggp + (size_t)N * D;       // N*D fp32 (packed h)
    unsigned short* w1_hi = (unsigned short*)(hpk + (size_t)N * D);
    unsigned short* w1_lo = w1_hi + 32768;
    unsigned short* w2_hi = w1_lo + 32768;
    unsigned short* w2_lo = w2_hi + 32768;
    unsigned short* fbf   = w2_lo + 32768;     // N*D bf16 (x -> h -> z, reused)

    const int nblk_gather = (N * 32 + 255) / 256;  // 6250
    const int ntiles = N / 16;                     // 3125
    const int nblk_gemm = (ntiles + 3) / 4;        // 782
    const int ncast = (N * D / 4 + 255) / 256;     // 6250
    const int nbC = (E + CCHUNK - 1) / CCHUNK;     // 196
    const int nbD = (N + 255) / 256;               // 196

    // weight pack + x cast (+ zero chist & csr pad in last cast block)
    wsplit_kernel<<<256, 256, 0, stream>>>(W1l, W1r, W2l, W2r, w1_hi, w1_lo, w2_hi, w2_lo);
    cast_bf16_kernel<<<ncast + 1, 256, 0, stream>>>(x, fbf, N * D / 4, chist, csr + E);

    // CSR build: coarse count -> scan -> coarse multisplit -> fine bucket
    coarse_count_kernel<<<256, 256, 0, stream>>>(dst, chist, E);
    scan256_kernel<<<1, 256, 0, stream>>>(chist, cbase, gcur);
    coarse_scatter_kernel<<<nbC, 256, 0, stream>>>(src, dst, gcur, centries, E);
    fine_bucket_kernel<<<nbD, 256, 0, stream>>>(centries, cbase, off, csr, N, E);

    // layer 1: h = relu(mean(x)@W1l + x@W1r + b1) -> hpk (packed) + fbf (bf16)
    gather_mean_kernel<<<nblk_gather, 256, 0, stream>>>(fbf, off, csr, aggp, N);
    sage_gemm_kernel<<<nblk_gemm, 256, 0, stream>>>(aggp, x, w1_hi, w1_lo, b1,
                                                    hpk, fbf, ntiles, 0, 1);
    // layer 2: z = mean(h)@W2l + h@W2r + b2 -> fbf (bf16 z)
    gather_mean_kernel<<<nblk_gather, 256, 0, stream>>>(fbf, off, csr, aggp, N);
    sage_gemm_kernel<<<nblk_gemm, 256, 0, stream>>>(aggp, hpk, w2_hi, w2_lo, b2,
                                                    (float*)nullptr, fbf, ntiles, 1, 0);
    // decode from bf16 z
    pred_kernel<<<(EP * 32 + 255) / 256, 256, 0, stream>>>(fbf, ps, pd, out, EP);
}